// Round 14
// baseline (234.793 us; speedup 1.0000x reference)
//
#include <hip/hip_runtime.h>

typedef __bf16 bf16_t;
typedef __bf16 bf16x8 __attribute__((ext_vector_type(8)));
typedef __bf16 bf16x4 __attribute__((ext_vector_type(4)));
typedef float f32x4 __attribute__((ext_vector_type(4)));

constexpr int BATCH = 8;
constexpr int NSEQ = 1024;
constexpr int DMODEL = 768;
constexpr int NH = 12;
constexpr int HDIM = 64;
constexpr int MROWS = BATCH * NSEQ;     // 8192
constexpr int WSZ = DMODEL * DMODEL;    // 589824
constexpr float L2E = 1.44269504088896f;

#define AS1(p) ((const __attribute__((address_space(1))) void*)(p))
#define AS3(p) ((__attribute__((address_space(3))) void*)(p))

// ---------------------------------------------------------------------------
// K0a: weights f32 -> bf16. 8*W_qs / 8*W_qt fold (x8 = exponent shift,
// bit-exact in bf16) removes all score/corr scaling from the attn loop.
// ---------------------------------------------------------------------------
__global__ __launch_bounds__(256) void prep_w(
    const float* __restrict__ wq, const float* __restrict__ wqt,
    const float* __restrict__ wk, const float* __restrict__ wv,
    const float* __restrict__ wp, const float* __restrict__ bq,
    const float* __restrict__ bqt, ushort* __restrict__ wb_,
    float* __restrict__ bqs, float* __restrict__ bqt8)
{
    int i = blockIdx.x * 256 + threadIdx.x;  // exactly 589824 threads
    bf16_t* w = (bf16_t*)wb_;
    float a = wq[i], b = wqt[i];
    w[i]            = (bf16_t)(8.0f * (a + b));   // 8*W_qs
    w[WSZ + i]      = (bf16_t)(8.0f * b);         // 8*W_qt
    w[2*WSZ + i]    = (bf16_t)wk[i];
    w[3*WSZ + i]    = (bf16_t)wv[i];
    w[4*WSZ + i]    = (bf16_t)wp[i];
    if (i < DMODEL) {
        bqs[i]  = 8.0f * (bq[i] + bqt[i]);
        bqt8[i] = 8.0f * bqt[i];
    }
}

// ---------------------------------------------------------------------------
// K0b: x f32 -> bf16
// ---------------------------------------------------------------------------
__global__ __launch_bounds__(256) void conv_x(const float* __restrict__ x,
                                              ushort* __restrict__ xb_)
{
    int i = (blockIdx.x * 256 + threadIdx.x) * 4;
    float4 v = *(const float4*)(x + i);
    bf16x4 r = { (bf16_t)v.x, (bf16_t)v.y, (bf16_t)v.z, (bf16_t)v.w };
    *(bf16x4*)((bf16_t*)xb_ + i) = r;
}

// ---------------------------------------------------------------------------
// Shared GEMM core: Y = A[M][768] * W[N][768]^T (bf16 in, f32 acc)
// block = 256 threads (4 waves, 2x2), tile 128x128, BK=64.
// Staging: global_load_lds width=16, LINEAR LDS dest, PRE-SWIZZLED global src.
// ---------------------------------------------------------------------------
__device__ __forceinline__ void gemm_core(
    const bf16_t* __restrict__ A, const bf16_t* __restrict__ W,
    bf16_t* As, bf16_t* Bs, int m0, int n0, int tid, f32x4 acc[4][4])
{
    const int lane = tid & 63, wave = tid >> 6;
    const int g = lane >> 4, c = lane & 15;
    const int wm = wave >> 1, wn = wave & 1;

    const int r_b = tid >> 3;
    const int koff = 8 * ((tid & 7) ^ (r_b & 7));
    const size_t arow = (size_t)(m0 + r_b) * DMODEL + koff;
    const size_t brow = (size_t)(n0 + r_b) * DMODEL + koff;
    char* As_base = (char*)As + (tid & ~63) * 16;   // per-wave uniform
    char* Bs_base = (char*)Bs + (tid & ~63) * 16;

    for (int k0 = 0; k0 < DMODEL; k0 += 64) {
        __syncthreads();
#pragma unroll
        for (int i = 0; i < 4; i++)
            __builtin_amdgcn_global_load_lds(
                AS1(A + arow + k0 + (size_t)i * 32 * DMODEL),
                AS3(As_base + i * 4096), 16, 0, 0);
#pragma unroll
        for (int i = 0; i < 4; i++)
            __builtin_amdgcn_global_load_lds(
                AS1(W + brow + k0 + (size_t)i * 32 * DMODEL),
                AS3(Bs_base + i * 4096), 16, 0, 0);
        __syncthreads();
#pragma unroll
        for (int kk = 0; kk < 2; kk++) {
            bf16x8 af[4], bfr[4];
#pragma unroll
            for (int mt = 0; mt < 4; mt++) {
                int r = wm * 64 + mt * 16 + c;
                af[mt] = *(const bf16x8*)(As + r * 64 + ((kk * 4 + g) ^ (r & 7)) * 8);
            }
#pragma unroll
            for (int nt = 0; nt < 4; nt++) {
                int r = wn * 64 + nt * 16 + c;
                bfr[nt] = *(const bf16x8*)(Bs + r * 64 + ((kk * 4 + g) ^ (r & 7)) * 8);
            }
#pragma unroll
            for (int mt = 0; mt < 4; mt++)
#pragma unroll
                for (int nt = 0; nt < 4; nt++)
                    acc[mt][nt] = __builtin_amdgcn_mfma_f32_16x16x32_bf16(
                        af[mt], bfr[nt], acc[mt][nt], 0, 0, 0);
        }
    }
}

// ---------------------------------------------------------------------------
// K1: fused QS/QT/K/V projection (1D grid, XCD-chunked).
// z<3 -> head layout [B][H][N][64]; z==3 (V) -> TRANSPOSED [B][H][64][N]
// (bf16x4 stores along seq — the r9-verified epilogue).
// ---------------------------------------------------------------------------
__global__ __launch_bounds__(256) void gemm_qkv(
    const ushort* __restrict__ xb_, const ushort* __restrict__ wb_,
    const float* __restrict__ bqs, const float* __restrict__ bqt8,
    const float* __restrict__ bk, const float* __restrict__ bv,
    ushort* __restrict__ o0, ushort* __restrict__ o1,
    ushort* __restrict__ o2, ushort* __restrict__ o3)
{
    __shared__ alignas(16) bf16_t As[128 * 64];
    __shared__ alignas(16) bf16_t Bs[128 * 64];
    const int bid = blockIdx.x;
    const int gid = (bid & 7) * 192 + (bid >> 3);
    const int z = gid / 384;
    const int rr = gid % 384;
    const int m0 = (rr / 6) * 128, n0 = (rr % 6) * 128;

    const bf16_t* A = (const bf16_t*)xb_;
    const bf16_t* W = (const bf16_t*)wb_ + (size_t)z * WSZ;
    const float* bias = (z == 0) ? bqs : (z == 1) ? bqt8 : (z == 2) ? bk : bv;
    bf16_t* outp = (bf16_t*)((z == 0) ? o0 : (z == 1) ? o1 : (z == 2) ? o2 : o3);
    f32x4 acc[4][4] = {};
    gemm_core(A, W, As, Bs, m0, n0, threadIdx.x, acc);

    const int tid = threadIdx.x, lane = tid & 63, wave = tid >> 6;
    const int g = lane >> 4, c = lane & 15;
    const int wm = wave >> 1, wn = wave & 1;
#pragma unroll
    for (int mt = 0; mt < 4; mt++)
#pragma unroll
        for (int nt = 0; nt < 4; nt++) {
            int col = n0 + wn * 64 + nt * 16 + c;
            int h = col >> 6, hd = col & 63;
            float bsv = bias[col];
            if (z == 3) {
                // V transposed: vT[(b*NH+h)*64 + hd][ns0 .. ns0+3]
                int row0 = m0 + wm * 64 + mt * 16 + 4 * g;
                int b = row0 >> 10, ns0 = row0 & 1023;
                bf16x4 pb = { (bf16_t)(acc[mt][nt][0] + bsv),
                              (bf16_t)(acc[mt][nt][1] + bsv),
                              (bf16_t)(acc[mt][nt][2] + bsv),
                              (bf16_t)(acc[mt][nt][3] + bsv) };
                *(bf16x4*)(outp + ((size_t)(b * NH + h) * HDIM + hd) * NSEQ + ns0) = pb;
            } else {
#pragma unroll
                for (int j = 0; j < 4; j++) {
                    int row = m0 + wm * 64 + mt * 16 + 4 * g + j;
                    int b = row >> 10, ns = row & 1023;
                    outp[(((size_t)b * NH + h) * NSEQ + ns) * HDIM + hd] =
                        (bf16_t)(acc[mt][nt][j] + bsv);
                }
            }
        }
}

// ---------------------------------------------------------------------------
// K3: output projection, f32 flat output into d_out (1D grid, XCD-chunked)
// ---------------------------------------------------------------------------
__global__ __launch_bounds__(256) void gemm_out(
    const ushort* __restrict__ ao_, const ushort* __restrict__ wp_,
    const float* __restrict__ bp, float* __restrict__ out)
{
    __shared__ alignas(16) bf16_t As[128 * 64];
    __shared__ alignas(16) bf16_t Bs[128 * 64];
    const int bid = blockIdx.x;
    const int gid = (bid & 7) * 48 + (bid >> 3);
    const int m0 = (gid / 6) * 128, n0 = (gid % 6) * 128;

    const bf16_t* A = (const bf16_t*)ao_;
    const bf16_t* W = (const bf16_t*)wp_;
    f32x4 acc[4][4] = {};
    gemm_core(A, W, As, Bs, m0, n0, threadIdx.x, acc);

    const int tid = threadIdx.x, lane = tid & 63, wave = tid >> 6;
    const int g = lane >> 4, c = lane & 15;
    const int wm = wave >> 1, wn = wave & 1;
#pragma unroll
    for (int mt = 0; mt < 4; mt++)
#pragma unroll
        for (int nt = 0; nt < 4; nt++) {
            int col = n0 + wn * 64 + nt * 16 + c;
            float bsv = bp[col];
#pragma unroll
            for (int j = 0; j < 4; j++) {
                int row = m0 + wm * 64 + mt * 16 + 4 * g + j;
                out[(size_t)row * DMODEL + col] = acc[mt][nt][j] + bsv;
            }
        }
}

// ---------------------------------------------------------------------------
// K2: depth-2 pipelined attn (r13) + STORES-NEWEST invariant restored:
// per iter issue order is now V(t+1) loads -> scores MFMAs (ca held in regs)
// -> kf(t+1) loads -> corr stores (NEWEST) -> softmax -> P -> PV -> V->LDS
// -> lgkm-only barrier. The scores(t+1) vmcnt wait on kf therefore never
// forces corr-store retirement (r7 mechanism, applied to the r13 pipeline).
// ---------------------------------------------------------------------------
__global__ __launch_bounds__(256, 2) void attn_kernel(
    const ushort* __restrict__ qs_, const ushort* __restrict__ qt_,
    const ushort* __restrict__ kb_, const ushort* __restrict__ vt_,
    ushort* __restrict__ ao_, float* __restrict__ corr)
{
    __shared__ alignas(16) bf16_t VT[2][64 * 64];   // [hd][ch^(hd&7) chunks]
    __shared__ alignas(16) bf16_t P[4][32 * 72];    // per-wave [q(32)][kv], pad 72
    const bf16_t* QS = (const bf16_t*)qs_;
    const bf16_t* QT = (const bf16_t*)qt_;
    const bf16_t* Kb = (const bf16_t*)kb_;
    const bf16_t* Vt = (const bf16_t*)vt_;
    bf16_t* Ob = (bf16_t*)ao_;

    const int tid = threadIdx.x;
    const int w = tid >> 6, lane = tid & 63;
    const int g = lane >> 4, c = lane & 15;
    // XCD-chunked swizzle: 768 = 8 x 96; 12 bh per XCD -> K/V L2-resident
    const int bid = blockIdx.x;
    const int gid = (bid & 7) * 96 + (bid >> 3);
    const int bh = gid >> 3, qb = gid & 7;
    const int q00 = qb * 128 + w * 32;              // wave owns rows q00..q00+31
    const size_t base = (size_t)bh * (NSEQ * HDIM);

    bf16x8 qsf[2][2], qtf[2][2];
#pragma unroll
    for (int s = 0; s < 2; s++)
#pragma unroll
        for (int kk = 0; kk < 2; kk++) {
            const size_t qrow = base + (size_t)(q00 + s * 16 + c) * HDIM + kk * 32 + 8 * g;
            qsf[s][kk] = *(const bf16x8*)(QS + qrow);
            qtf[s][kk] = *(const bf16x8*)(QT + qrow);
        }
    f32x4 oacc[2][4] = {};
    float mrun[2], lrun[2];
#pragma unroll
    for (int s = 0; s < 2; s++) { mrun[s] = -3e30f; lrun[s] = 0.f; }

    float* corr_b = corr + (size_t)bh * (NSEQ * NSEQ);

    // staging geometry (loop-invariant)
    const int hd0_ = tid >> 3, ch0_ = tid & 7;
    const int hd1_ = hd0_ + 32;
    const int vtoff0 = hd0_ * 64 + (ch0_ ^ (hd0_ & 7)) * 8;
    const int vtoff1 = hd1_ * 64 + (ch0_ ^ (hd1_ & 7)) * 8;

    // ---- PROLOGUE: prefetch tile 0 (V->regs->LDS, K->kf), barrier ----
    bf16x8 vrA = *(const bf16x8*)(Vt + base + (size_t)hd0_ * NSEQ + ch0_ * 8);
    bf16x8 vrB = *(const bf16x8*)(Vt + base + (size_t)hd1_ * NSEQ + ch0_ * 8);
    bf16x8 kf[4][2];
#pragma unroll
    for (int kvt = 0; kvt < 4; kvt++) {
        const size_t krow = base + (size_t)(kvt * 16 + c) * HDIM + 8 * g;
        kf[kvt][0] = *(const bf16x8*)(Kb + krow);
        kf[kvt][1] = *(const bf16x8*)(Kb + krow + 32);
    }
    *(bf16x8*)(VT[0] + vtoff0) = vrA;
    *(bf16x8*)(VT[0] + vtoff1) = vrB;
    asm volatile("s_waitcnt lgkmcnt(0)" ::: "memory");
    __builtin_amdgcn_sched_barrier(0);
    __builtin_amdgcn_s_barrier();

    for (int t = 0; t < 16; t++) {
        const int kv0 = t * 64;
        const int kvn = kv0 + 64;
        bf16_t* vtc = VT[t & 1];
        bf16_t* vtn = VT[(t + 1) & 1];
        // ---- prefetch V(t+1) global -> regs (consumed after PV) ----
        if (t < 15) {
            vrA = *(const bf16x8*)(Vt + base + (size_t)hd0_ * NSEQ + kvn + ch0_ * 8);
            vrB = *(const bf16x8*)(Vt + base + (size_t)hd1_ * NSEQ + kvn + ch0_ * 8);
        }
        // ---- scores + corr MFMAs (kf from last iter; ca held in regs) ----
        f32x4 sv[2][4];
        f32x4 caH[2][4];
#pragma unroll
        for (int kvt = 0; kvt < 4; kvt++) {
#pragma unroll
            for (int s = 0; s < 2; s++) {
                f32x4 sa = {0.f, 0.f, 0.f, 0.f};
                f32x4 ca = {0.f, 0.f, 0.f, 0.f};
                sa = __builtin_amdgcn_mfma_f32_16x16x32_bf16(kf[kvt][0], qsf[s][0], sa, 0, 0, 0);
                sa = __builtin_amdgcn_mfma_f32_16x16x32_bf16(kf[kvt][1], qsf[s][1], sa, 0, 0, 0);
                ca = __builtin_amdgcn_mfma_f32_16x16x32_bf16(kf[kvt][0], qtf[s][0], ca, 0, 0, 0);
                ca = __builtin_amdgcn_mfma_f32_16x16x32_bf16(kf[kvt][1], qtf[s][1], ca, 0, 0, 0);
                sv[s][kvt] = sa;
                caH[s][kvt] = ca;
            }
        }
        // ---- prefetch K(t+1) into kf BEFORE the stores (loads older) ----
        if (t < 15) {
#pragma unroll
            for (int kvt = 0; kvt < 4; kvt++) {
                const size_t krow = base + (size_t)(kvn + kvt * 16 + c) * HDIM + 8 * g;
                kf[kvt][0] = *(const bf16x8*)(Kb + krow);
                kf[kvt][1] = *(const bf16x8*)(Kb + krow + 32);
            }
        }
        // ---- corr stores: NEWEST VMEM ops; ack under softmax+PV+barrier ----
#pragma unroll
        for (int s = 0; s < 2; s++)
#pragma unroll
            for (int kvt = 0; kvt < 4; kvt++)
                *(f32x4*)(corr_b + (size_t)(q00 + s * 16 + c) * NSEQ + kv0 + kvt * 16 + 4 * g) = caH[s][kvt];
        // ---- per-set online softmax + P write ----
#pragma unroll
        for (int s = 0; s < 2; s++) {
            f32x4 mm;
#pragma unroll
            for (int j = 0; j < 4; j++)
                mm[j] = fmaxf(fmaxf(sv[s][0][j], sv[s][1][j]),
                              fmaxf(sv[s][2][j], sv[s][3][j]));
            float tm = fmaxf(fmaxf(mm[0], mm[1]), fmaxf(mm[2], mm[3]));
            tm = fmaxf(tm, __shfl_xor(tm, 16));
            tm = fmaxf(tm, __shfl_xor(tm, 32));
            if (__any(tm > mrun[s] + 8.0f)) {
                float newm = fmaxf(mrun[s], tm);
                float scl = exp2f((mrun[s] - newm) * L2E);
                mrun[s] = newm;
                lrun[s] *= scl;
#pragma unroll
                for (int j = 0; j < 4; j++) {
                    float scj = __shfl(scl, 4 * g + j);
#pragma unroll
                    for (int nt = 0; nt < 4; nt++) oacc[s][nt][j] *= scj;
                }
            }
            const float mneg = mrun[s] * L2E;
            float ps = 0.f;
#pragma unroll
            for (int kvt = 0; kvt < 4; kvt++)
#pragma unroll
                for (int j = 0; j < 4; j++) {
                    float p = exp2f(__builtin_fmaf(sv[s][kvt][j], L2E, -mneg));
                    sv[s][kvt][j] = p;
                    ps += p;
                }
            ps += __shfl_xor(ps, 16);
            ps += __shfl_xor(ps, 32);
            lrun[s] += ps;
#pragma unroll
            for (int kvt = 0; kvt < 4; kvt++) {
                bf16x4 pb = { (bf16_t)sv[s][kvt][0], (bf16_t)sv[s][kvt][1],
                              (bf16_t)sv[s][kvt][2], (bf16_t)sv[s][kvt][3] };
                *(bf16x4*)(&P[w][(s * 16 + c) * 72 + kvt * 16 + 4 * g]) = pb;
            }
        }
        // ---- PV(t): oacc += P * V  (VT[t&1]; P same-wave lgkm) ----
#pragma unroll
        for (int kk = 0; kk < 2; kk++) {
#pragma unroll
            for (int nt = 0; nt < 4; nt++) {
                const int hd = nt * 16 + c;
                bf16x8 vf = *(const bf16x8*)(&vtc[hd * 64 + (((kk * 4 + g) ^ (hd & 7)) * 8)]);
#pragma unroll
                for (int s = 0; s < 2; s++) {
                    bf16x8 pa = *(const bf16x8*)(&P[w][(s * 16 + c) * 72 + kk * 32 + 8 * g]);
                    oacc[s][nt] = __builtin_amdgcn_mfma_f32_16x16x32_bf16(pa, vf, oacc[s][nt], 0, 0, 0);
                }
            }
        }
        // ---- write prefetched V regs -> VT[(t+1)&1] (latency long hidden) ----
        if (t < 15) {
            *(bf16x8*)(vtn + vtoff0) = vrA;
            *(bf16x8*)(vtn + vtoff1) = vrB;
        }
        // ---- raw barrier: drain OWN LDS ops; vmcnt left counting ----
        asm volatile("s_waitcnt lgkmcnt(0)" ::: "memory");
        __builtin_amdgcn_sched_barrier(0);
        __builtin_amdgcn_s_barrier();
    }
    // ---- normalize + store attention output (bf16, [B*N][768] flat) ----
    const int b = bh / NH, h = bh % NH;
#pragma unroll
    for (int s = 0; s < 2; s++) {
        float lj[4];
#pragma unroll
        for (int j = 0; j < 4; j++) lj[j] = __shfl(lrun[s], 4 * g + j);
#pragma unroll
        for (int nt = 0; nt < 4; nt++)
#pragma unroll
            for (int j = 0; j < 4; j++) {
                float val = oacc[s][nt][j] / lj[j];
                Ob[(size_t)(b * NSEQ + q00 + s * 16 + 4 * g + j) * DMODEL + h * HDIM + nt * 16 + c] =
                    (bf16_t)val;
            }
    }
}

// ---------------------------------------------------------------------------
extern "C" void kernel_launch(void* const* d_in, const int* in_sizes, int n_in,
                              void* d_out, int out_size, void* d_ws, size_t ws_size,
                              hipStream_t stream)
{
    const float* x   = (const float*)d_in[0];
    const float* wq  = (const float*)d_in[1];
    const float* bq  = (const float*)d_in[2];
    const float* wk  = (const float*)d_in[3];
    const float* bk  = (const float*)d_in[4];
    const float* wv  = (const float*)d_in[5];
    const float* bv  = (const float*)d_in[6];
    const float* wqt = (const float*)d_in[7];
    const float* bqt = (const float*)d_in[8];
    const float* wp  = (const float*)d_in[9];
    const float* bp  = (const float*)d_in[10];

    char* ws = (char*)d_ws;
    ushort* xb   = (ushort*)(ws);                         // 8192*768 bf16
    ushort* wb   = (ushort*)(ws + 12582912);              // 5 * 589824 bf16
    float*  bqs  = (float*)(ws + 18481152);               // 768 f32 (8*(bq+bqt))
    float*  bqt8 = (float*)(ws + 18485248);               // 768 f32 (8*bqt)
    ushort* qs   = (ushort*)(ws + 18489344);              // head-layout bufs
    ushort* qt   = qs + 6291456;
    ushort* kb   = qt + 6291456;
    ushort* vt   = kb + 6291456;                          // V TRANSPOSED [bh][hd][n]
    ushort* ao   = vt + 6291456;

    float* out  = (float*)d_out;
    float* corr = out + (size_t)6291456;

    prep_w<<<2304, 256, 0, stream>>>(wq, wqt, wk, wv, wp, bq, bqt, wb, bqs, bqt8);
    conv_x<<<6144, 256, 0, stream>>>(x, xb);
    gemm_qkv<<<1536, 256, 0, stream>>>(xb, wb, bqs, bqt8, bk, bv, qs, qt, kb, vt);
    attn_kernel<<<768, 256, 0, stream>>>(qs, qt, kb, vt, ao, corr);
    gemm_out<<<384, 256, 0, stream>>>(ao, wb + (size_t)4 * WSZ, bp, out);
}

// Round 15
// 221.102 us; speedup vs baseline: 1.0619x; 1.0619x over previous
//
#include <hip/hip_runtime.h>

typedef __bf16 bf16_t;
typedef __bf16 bf16x8 __attribute__((ext_vector_type(8)));
typedef __bf16 bf16x4 __attribute__((ext_vector_type(4)));
typedef float f32x4 __attribute__((ext_vector_type(4)));

constexpr int BATCH = 8;
constexpr int NSEQ = 1024;
constexpr int DMODEL = 768;
constexpr int NH = 12;
constexpr int HDIM = 64;
constexpr int MROWS = BATCH * NSEQ;     // 8192
constexpr int WSZ = DMODEL * DMODEL;    // 589824
constexpr float L2E = 1.44269504088896f;

#define AS1(p) ((const __attribute__((address_space(1))) void*)(p))
#define AS3(p) ((__attribute__((address_space(3))) void*)(p))

// ---------------------------------------------------------------------------
// K0a: weights f32 -> bf16. 8*W_qs / 8*W_qt fold (x8 = exponent shift,
// bit-exact in bf16) removes all score/corr scaling from the attn loop.
// ---------------------------------------------------------------------------
__global__ __launch_bounds__(256) void prep_w(
    const float* __restrict__ wq, const float* __restrict__ wqt,
    const float* __restrict__ wk, const float* __restrict__ wv,
    const float* __restrict__ wp, const float* __restrict__ bq,
    const float* __restrict__ bqt, ushort* __restrict__ wb_,
    float* __restrict__ bqs, float* __restrict__ bqt8)
{
    int i = blockIdx.x * 256 + threadIdx.x;  // exactly 589824 threads
    bf16_t* w = (bf16_t*)wb_;
    float a = wq[i], b = wqt[i];
    w[i]            = (bf16_t)(8.0f * (a + b));   // 8*W_qs
    w[WSZ + i]      = (bf16_t)(8.0f * b);         // 8*W_qt
    w[2*WSZ + i]    = (bf16_t)wk[i];
    w[3*WSZ + i]    = (bf16_t)wv[i];
    w[4*WSZ + i]    = (bf16_t)wp[i];
    if (i < DMODEL) {
        bqs[i]  = 8.0f * (bq[i] + bqt[i]);
        bqt8[i] = 8.0f * bqt[i];
    }
}

// ---------------------------------------------------------------------------
// K0b: x f32 -> bf16
// ---------------------------------------------------------------------------
__global__ __launch_bounds__(256) void conv_x(const float* __restrict__ x,
                                              ushort* __restrict__ xb_)
{
    int i = (blockIdx.x * 256 + threadIdx.x) * 4;
    float4 v = *(const float4*)(x + i);
    bf16x4 r = { (bf16_t)v.x, (bf16_t)v.y, (bf16_t)v.z, (bf16_t)v.w };
    *(bf16x4*)((bf16_t*)xb_ + i) = r;
}

// ---------------------------------------------------------------------------
// Shared GEMM core: Y = A[M][768] * W[N][768]^T (bf16 in, f32 acc)
// block = 256 threads (4 waves, 2x2), tile 128x128, BK=64.
// Staging: global_load_lds width=16, LINEAR LDS dest, PRE-SWIZZLED global src.
// ---------------------------------------------------------------------------
__device__ __forceinline__ void gemm_core(
    const bf16_t* __restrict__ A, const bf16_t* __restrict__ W,
    bf16_t* As, bf16_t* Bs, int m0, int n0, int tid, f32x4 acc[4][4])
{
    const int lane = tid & 63, wave = tid >> 6;
    const int g = lane >> 4, c = lane & 15;
    const int wm = wave >> 1, wn = wave & 1;

    const int r_b = tid >> 3;
    const int koff = 8 * ((tid & 7) ^ (r_b & 7));
    const size_t arow = (size_t)(m0 + r_b) * DMODEL + koff;
    const size_t brow = (size_t)(n0 + r_b) * DMODEL + koff;
    char* As_base = (char*)As + (tid & ~63) * 16;   // per-wave uniform
    char* Bs_base = (char*)Bs + (tid & ~63) * 16;

    for (int k0 = 0; k0 < DMODEL; k0 += 64) {
        __syncthreads();
#pragma unroll
        for (int i = 0; i < 4; i++)
            __builtin_amdgcn_global_load_lds(
                AS1(A + arow + k0 + (size_t)i * 32 * DMODEL),
                AS3(As_base + i * 4096), 16, 0, 0);
#pragma unroll
        for (int i = 0; i < 4; i++)
            __builtin_amdgcn_global_load_lds(
                AS1(W + brow + k0 + (size_t)i * 32 * DMODEL),
                AS3(Bs_base + i * 4096), 16, 0, 0);
        __syncthreads();
#pragma unroll
        for (int kk = 0; kk < 2; kk++) {
            bf16x8 af[4], bfr[4];
#pragma unroll
            for (int mt = 0; mt < 4; mt++) {
                int r = wm * 64 + mt * 16 + c;
                af[mt] = *(const bf16x8*)(As + r * 64 + ((kk * 4 + g) ^ (r & 7)) * 8);
            }
#pragma unroll
            for (int nt = 0; nt < 4; nt++) {
                int r = wn * 64 + nt * 16 + c;
                bfr[nt] = *(const bf16x8*)(Bs + r * 64 + ((kk * 4 + g) ^ (r & 7)) * 8);
            }
#pragma unroll
            for (int mt = 0; mt < 4; mt++)
#pragma unroll
                for (int nt = 0; nt < 4; nt++)
                    acc[mt][nt] = __builtin_amdgcn_mfma_f32_16x16x32_bf16(
                        af[mt], bfr[nt], acc[mt][nt], 0, 0, 0);
        }
    }
}

// ---------------------------------------------------------------------------
// K1: fused QS/QT/K/V projection (1D grid, XCD-chunked).
// z<3 -> head layout [B][H][N][64]; z==3 (V) -> TRANSPOSED [B][H][64][N]
// (bf16x4 stores along seq — the r9-verified epilogue).
// ---------------------------------------------------------------------------
__global__ __launch_bounds__(256) void gemm_qkv(
    const ushort* __restrict__ xb_, const ushort* __restrict__ wb_,
    const float* __restrict__ bqs, const float* __restrict__ bqt8,
    const float* __restrict__ bk, const float* __restrict__ bv,
    ushort* __restrict__ o0, ushort* __restrict__ o1,
    ushort* __restrict__ o2, ushort* __restrict__ o3)
{
    __shared__ alignas(16) bf16_t As[128 * 64];
    __shared__ alignas(16) bf16_t Bs[128 * 64];
    const int bid = blockIdx.x;
    const int gid = (bid & 7) * 192 + (bid >> 3);
    const int z = gid / 384;
    const int rr = gid % 384;
    const int m0 = (rr / 6) * 128, n0 = (rr % 6) * 128;

    const bf16_t* A = (const bf16_t*)xb_;
    const bf16_t* W = (const bf16_t*)wb_ + (size_t)z * WSZ;
    const float* bias = (z == 0) ? bqs : (z == 1) ? bqt8 : (z == 2) ? bk : bv;
    bf16_t* outp = (bf16_t*)((z == 0) ? o0 : (z == 1) ? o1 : (z == 2) ? o2 : o3);
    f32x4 acc[4][4] = {};
    gemm_core(A, W, As, Bs, m0, n0, threadIdx.x, acc);

    const int tid = threadIdx.x, lane = tid & 63, wave = tid >> 6;
    const int g = lane >> 4, c = lane & 15;
    const int wm = wave >> 1, wn = wave & 1;
#pragma unroll
    for (int mt = 0; mt < 4; mt++)
#pragma unroll
        for (int nt = 0; nt < 4; nt++) {
            int col = n0 + wn * 64 + nt * 16 + c;
            int h = col >> 6, hd = col & 63;
            float bsv = bias[col];
            if (z == 3) {
                // V transposed: vT[(b*NH+h)*64 + hd][ns0 .. ns0+3]
                int row0 = m0 + wm * 64 + mt * 16 + 4 * g;
                int b = row0 >> 10, ns0 = row0 & 1023;
                bf16x4 pb = { (bf16_t)(acc[mt][nt][0] + bsv),
                              (bf16_t)(acc[mt][nt][1] + bsv),
                              (bf16_t)(acc[mt][nt][2] + bsv),
                              (bf16_t)(acc[mt][nt][3] + bsv) };
                *(bf16x4*)(outp + ((size_t)(b * NH + h) * HDIM + hd) * NSEQ + ns0) = pb;
            } else {
#pragma unroll
                for (int j = 0; j < 4; j++) {
                    int row = m0 + wm * 64 + mt * 16 + 4 * g + j;
                    int b = row >> 10, ns = row & 1023;
                    outp[(((size_t)b * NH + h) * NSEQ + ns) * HDIM + hd] =
                        (bf16_t)(acc[mt][nt][j] + bsv);
                }
            }
        }
}

// ---------------------------------------------------------------------------
// K3: output projection, f32 flat output into d_out (1D grid, XCD-chunked)
// ---------------------------------------------------------------------------
__global__ __launch_bounds__(256) void gemm_out(
    const ushort* __restrict__ ao_, const ushort* __restrict__ wp_,
    const float* __restrict__ bp, float* __restrict__ out)
{
    __shared__ alignas(16) bf16_t As[128 * 64];
    __shared__ alignas(16) bf16_t Bs[128 * 64];
    const int bid = blockIdx.x;
    const int gid = (bid & 7) * 48 + (bid >> 3);
    const int m0 = (gid / 6) * 128, n0 = (gid % 6) * 128;

    const bf16_t* A = (const bf16_t*)ao_;
    const bf16_t* W = (const bf16_t*)wp_;
    f32x4 acc[4][4] = {};
    gemm_core(A, W, As, Bs, m0, n0, threadIdx.x, acc);

    const int tid = threadIdx.x, lane = tid & 63, wave = tid >> 6;
    const int g = lane >> 4, c = lane & 15;
    const int wm = wave >> 1, wn = wave & 1;
#pragma unroll
    for (int mt = 0; mt < 4; mt++)
#pragma unroll
        for (int nt = 0; nt < 4; nt++) {
            int col = n0 + wn * 64 + nt * 16 + c;
            float bsv = bp[col];
#pragma unroll
            for (int j = 0; j < 4; j++) {
                int row = m0 + wm * 64 + mt * 16 + 4 * g + j;
                out[(size_t)row * DMODEL + col] = acc[mt][nt][j] + bsv;
            }
        }
}

// ---------------------------------------------------------------------------
// K2: depth-2 pipelined attn (r13 EXACT base, 224.5us) + T5 setprio around
// the two MFMA clusters. r14's stores-reorder reverted (VGPR overflow).
// Iter: [V(t+1)->reg] -> setprio{scores+corr MFMAs} -> softmax -> P ->
//       [K(t+1)->kf] -> setprio{PV} -> [Vregs->LDS] -> lgkm-only barrier.
// ---------------------------------------------------------------------------
__global__ __launch_bounds__(256, 2) void attn_kernel(
    const ushort* __restrict__ qs_, const ushort* __restrict__ qt_,
    const ushort* __restrict__ kb_, const ushort* __restrict__ vt_,
    ushort* __restrict__ ao_, float* __restrict__ corr)
{
    __shared__ alignas(16) bf16_t VT[2][64 * 64];   // [hd][ch^(hd&7) chunks]
    __shared__ alignas(16) bf16_t P[4][32 * 72];    // per-wave [q(32)][kv], pad 72
    const bf16_t* QS = (const bf16_t*)qs_;
    const bf16_t* QT = (const bf16_t*)qt_;
    const bf16_t* Kb = (const bf16_t*)kb_;
    const bf16_t* Vt = (const bf16_t*)vt_;
    bf16_t* Ob = (bf16_t*)ao_;

    const int tid = threadIdx.x;
    const int w = tid >> 6, lane = tid & 63;
    const int g = lane >> 4, c = lane & 15;
    // XCD-chunked swizzle: 768 = 8 x 96; 12 bh per XCD -> K/V L2-resident
    const int bid = blockIdx.x;
    const int gid = (bid & 7) * 96 + (bid >> 3);
    const int bh = gid >> 3, qb = gid & 7;
    const int q00 = qb * 128 + w * 32;              // wave owns rows q00..q00+31
    const size_t base = (size_t)bh * (NSEQ * HDIM);

    bf16x8 qsf[2][2], qtf[2][2];
#pragma unroll
    for (int s = 0; s < 2; s++)
#pragma unroll
        for (int kk = 0; kk < 2; kk++) {
            const size_t qrow = base + (size_t)(q00 + s * 16 + c) * HDIM + kk * 32 + 8 * g;
            qsf[s][kk] = *(const bf16x8*)(QS + qrow);
            qtf[s][kk] = *(const bf16x8*)(QT + qrow);
        }
    f32x4 oacc[2][4] = {};
    float mrun[2], lrun[2];
#pragma unroll
    for (int s = 0; s < 2; s++) { mrun[s] = -3e30f; lrun[s] = 0.f; }

    float* corr_b = corr + (size_t)bh * (NSEQ * NSEQ);

    // staging geometry (loop-invariant)
    const int hd0_ = tid >> 3, ch0_ = tid & 7;
    const int hd1_ = hd0_ + 32;
    const int vtoff0 = hd0_ * 64 + (ch0_ ^ (hd0_ & 7)) * 8;
    const int vtoff1 = hd1_ * 64 + (ch0_ ^ (hd1_ & 7)) * 8;

    // ---- PROLOGUE: prefetch tile 0 (V->regs->LDS, K->kf), barrier ----
    bf16x8 vrA = *(const bf16x8*)(Vt + base + (size_t)hd0_ * NSEQ + ch0_ * 8);
    bf16x8 vrB = *(const bf16x8*)(Vt + base + (size_t)hd1_ * NSEQ + ch0_ * 8);
    bf16x8 kf[4][2];
#pragma unroll
    for (int kvt = 0; kvt < 4; kvt++) {
        const size_t krow = base + (size_t)(kvt * 16 + c) * HDIM + 8 * g;
        kf[kvt][0] = *(const bf16x8*)(Kb + krow);
        kf[kvt][1] = *(const bf16x8*)(Kb + krow + 32);
    }
    *(bf16x8*)(VT[0] + vtoff0) = vrA;
    *(bf16x8*)(VT[0] + vtoff1) = vrB;
    asm volatile("s_waitcnt lgkmcnt(0)" ::: "memory");
    __builtin_amdgcn_sched_barrier(0);
    __builtin_amdgcn_s_barrier();

    for (int t = 0; t < 16; t++) {
        const int kv0 = t * 64;
        const int kvn = kv0 + 64;
        bf16_t* vtc = VT[t & 1];
        bf16_t* vtn = VT[(t + 1) & 1];
        // ---- prefetch V(t+1) global -> regs (consumed after PV) ----
        if (t < 15) {
            vrA = *(const bf16x8*)(Vt + base + (size_t)hd0_ * NSEQ + kvn + ch0_ * 8);
            vrB = *(const bf16x8*)(Vt + base + (size_t)hd1_ * NSEQ + kvn + ch0_ * 8);
        }
        // ---- scores + corr from kf (loaded last iter; latency hidden) ----
        __builtin_amdgcn_s_setprio(1);
        f32x4 sv[2][4];
#pragma unroll
        for (int kvt = 0; kvt < 4; kvt++) {
#pragma unroll
            for (int s = 0; s < 2; s++) {
                f32x4 sa = {0.f, 0.f, 0.f, 0.f};
                f32x4 ca = {0.f, 0.f, 0.f, 0.f};
                sa = __builtin_amdgcn_mfma_f32_16x16x32_bf16(kf[kvt][0], qsf[s][0], sa, 0, 0, 0);
                sa = __builtin_amdgcn_mfma_f32_16x16x32_bf16(kf[kvt][1], qsf[s][1], sa, 0, 0, 0);
                ca = __builtin_amdgcn_mfma_f32_16x16x32_bf16(kf[kvt][0], qtf[s][0], ca, 0, 0, 0);
                ca = __builtin_amdgcn_mfma_f32_16x16x32_bf16(kf[kvt][1], qtf[s][1], ca, 0, 0, 0);
                sv[s][kvt] = sa;
                *(f32x4*)(corr_b + (size_t)(q00 + s * 16 + c) * NSEQ + kv0 + kvt * 16 + 4 * g) = ca;
            }
        }
        __builtin_amdgcn_s_setprio(0);
        // ---- per-set online softmax + P write ----
#pragma unroll
        for (int s = 0; s < 2; s++) {
            f32x4 mm;
#pragma unroll
            for (int j = 0; j < 4; j++)
                mm[j] = fmaxf(fmaxf(sv[s][0][j], sv[s][1][j]),
                              fmaxf(sv[s][2][j], sv[s][3][j]));
            float tm = fmaxf(fmaxf(mm[0], mm[1]), fmaxf(mm[2], mm[3]));
            tm = fmaxf(tm, __shfl_xor(tm, 16));
            tm = fmaxf(tm, __shfl_xor(tm, 32));
            if (__any(tm > mrun[s] + 8.0f)) {
                float newm = fmaxf(mrun[s], tm);
                float scl = exp2f((mrun[s] - newm) * L2E);
                mrun[s] = newm;
                lrun[s] *= scl;
#pragma unroll
                for (int j = 0; j < 4; j++) {
                    float scj = __shfl(scl, 4 * g + j);
#pragma unroll
                    for (int nt = 0; nt < 4; nt++) oacc[s][nt][j] *= scj;
                }
            }
            const float mneg = mrun[s] * L2E;
            float ps = 0.f;
#pragma unroll
            for (int kvt = 0; kvt < 4; kvt++)
#pragma unroll
                for (int j = 0; j < 4; j++) {
                    float p = exp2f(__builtin_fmaf(sv[s][kvt][j], L2E, -mneg));
                    sv[s][kvt][j] = p;
                    ps += p;
                }
            ps += __shfl_xor(ps, 16);
            ps += __shfl_xor(ps, 32);
            lrun[s] += ps;
#pragma unroll
            for (int kvt = 0; kvt < 4; kvt++) {
                bf16x4 pb = { (bf16_t)sv[s][kvt][0], (bf16_t)sv[s][kvt][1],
                              (bf16_t)sv[s][kvt][2], (bf16_t)sv[s][kvt][3] };
                *(bf16x4*)(&P[w][(s * 16 + c) * 72 + kvt * 16 + 4 * g]) = pb;
            }
        }
        // ---- prefetch K(t+1) into kf (dead after scores); hides under PV ----
        if (t < 15) {
#pragma unroll
            for (int kvt = 0; kvt < 4; kvt++) {
                const size_t krow = base + (size_t)(kvn + kvt * 16 + c) * HDIM + 8 * g;
                kf[kvt][0] = *(const bf16x8*)(Kb + krow);
                kf[kvt][1] = *(const bf16x8*)(Kb + krow + 32);
            }
        }
        // ---- PV(t): oacc += P * V  (VT[t&1]; P same-wave lgkm) ----
        __builtin_amdgcn_s_setprio(1);
#pragma unroll
        for (int kk = 0; kk < 2; kk++) {
#pragma unroll
            for (int nt = 0; nt < 4; nt++) {
                const int hd = nt * 16 + c;
                bf16x8 vf = *(const bf16x8*)(&vtc[hd * 64 + (((kk * 4 + g) ^ (hd & 7)) * 8)]);
#pragma unroll
                for (int s = 0; s < 2; s++) {
                    bf16x8 pa = *(const bf16x8*)(&P[w][(s * 16 + c) * 72 + kk * 32 + 8 * g]);
                    oacc[s][nt] = __builtin_amdgcn_mfma_f32_16x16x32_bf16(pa, vf, oacc[s][nt], 0, 0, 0);
                }
            }
        }
        __builtin_amdgcn_s_setprio(0);
        // ---- write prefetched V regs -> VT[(t+1)&1] (latency long hidden) ----
        if (t < 15) {
            *(bf16x8*)(vtn + vtoff0) = vrA;
            *(bf16x8*)(vtn + vtoff1) = vrB;
        }
        // ---- raw barrier: drain OWN LDS ops; vmcnt left counting ----
        asm volatile("s_waitcnt lgkmcnt(0)" ::: "memory");
        __builtin_amdgcn_sched_barrier(0);
        __builtin_amdgcn_s_barrier();
    }
    // ---- normalize + store attention output (bf16, [B*N][768] flat) ----
    const int b = bh / NH, h = bh % NH;
#pragma unroll
    for (int s = 0; s < 2; s++) {
        float lj[4];
#pragma unroll
        for (int j = 0; j < 4; j++) lj[j] = __shfl(lrun[s], 4 * g + j);
#pragma unroll
        for (int nt = 0; nt < 4; nt++)
#pragma unroll
            for (int j = 0; j < 4; j++) {
                float val = oacc[s][nt][j] / lj[j];
                Ob[(size_t)(b * NSEQ + q00 + s * 16 + 4 * g + j) * DMODEL + h * HDIM + nt * 16 + c] =
                    (bf16_t)val;
            }
    }
}

// ---------------------------------------------------------------------------
extern "C" void kernel_launch(void* const* d_in, const int* in_sizes, int n_in,
                              void* d_out, int out_size, void* d_ws, size_t ws_size,
                              hipStream_t stream)
{
    const float* x   = (const float*)d_in[0];
    const float* wq  = (const float*)d_in[1];
    const float* bq  = (const float*)d_in[2];
    const float* wk  = (const float*)d_in[3];
    const float* bk  = (const float*)d_in[4];
    const float* wv  = (const float*)d_in[5];
    const float* bv  = (const float*)d_in[6];
    const float* wqt = (const float*)d_in[7];
    const float* bqt = (const float*)d_in[8];
    const float* wp  = (const float*)d_in[9];
    const float* bp  = (const float*)d_in[10];

    char* ws = (char*)d_ws;
    ushort* xb   = (ushort*)(ws);                         // 8192*768 bf16
    ushort* wb   = (ushort*)(ws + 12582912);              // 5 * 589824 bf16
    float*  bqs  = (float*)(ws + 18481152);               // 768 f32 (8*(bq+bqt))
    float*  bqt8 = (float*)(ws + 18485248);               // 768 f32 (8*bqt)
    ushort* qs   = (ushort*)(ws + 18489344);              // head-layout bufs
    ushort* qt   = qs + 6291456;
    ushort* kb   = qt + 6291456;
    ushort* vt   = kb + 6291456;                          // V TRANSPOSED [bh][hd][n]
    ushort* ao   = vt + 6291456;

    float* out  = (float*)d_out;
    float* corr = out + (size_t)6291456;

    prep_w<<<2304, 256, 0, stream>>>(wq, wqt, wk, wv, wp, bq, bqt, wb, bqs, bqt8);
    conv_x<<<6144, 256, 0, stream>>>(x, xb);
    gemm_qkv<<<1536, 256, 0, stream>>>(xb, wb, bqs, bqt8, bk, bv, qs, qt, kb, vt);
    attn_kernel<<<768, 256, 0, stream>>>(qs, qt, kb, vt, ao, corr);
    gemm_out<<<384, 256, 0, stream>>>(ao, wb + (size_t)4 * WSZ, bp, out);
}